// Round 1
// baseline (173.940 us; speedup 1.0000x reference)
//
#include <hip/hip_runtime.h>

#define POOL 7
#define NUM_ROIS 600
#define IMG_H 96
#define IMG_W 96
#define IMG_C 1024

typedef float v4f __attribute__((ext_vector_type(4)));

// ---------------------------------------------------------------------------
// Pass 1: counting-sort ROI indices by Morton code of their (x>>3, y>>3) bin.
// Spatially neighboring ROIs become adjacent in perm[] -> concurrent blocks
// on an XCD read overlapping image rows (cross-ROI L2 reuse). ~3 us.
// ---------------------------------------------------------------------------
__global__ __launch_bounds__(640) void bin_rois_kernel(
    const int* __restrict__ rois, int* __restrict__ perm)
{
    __shared__ int cnt[64];
    __shared__ int base[64];
    const int t = threadIdx.x;
    if (t < 64) cnt[t] = 0;
    __syncthreads();

    int mybin = 0;
    if (t < NUM_ROIS) {
        const int x = rois[t * 4 + 0];
        const int y = rois[t * 4 + 1];
        const int bx = min(max(x, 0), 63) >> 3;   // 0..7
        const int by = min(max(y, 0), 63) >> 3;   // 0..7
        mybin = (bx & 1) | ((by & 1) << 1) | ((bx & 2) << 1) |
                ((by & 2) << 2) | ((bx & 4) << 2) | ((by & 4) << 3);
        atomicAdd(&cnt[mybin], 1);
    }
    __syncthreads();
    if (t == 0) {
        int s = 0;
        for (int i = 0; i < 64; ++i) { base[i] = s; s += cnt[i]; cnt[i] = 0; }
    }
    __syncthreads();
    if (t < NUM_ROIS) {
        const int pos = base[mybin] + atomicAdd(&cnt[mybin], 1);
        perm[pos] = t;
    }
}

// ---------------------------------------------------------------------------
// Pass 2: block per (sorted_pos, py), 1024 threads as (256 ch-lanes, 4 px
// streams). Each y-stream does px = ty and px = ty+4 (ty==3 skips the 2nd).
//
// R6 change (discriminating experiment): skip corner loads whose bilinear
// weight is exactly 0.0f.  fx==0 always for px==0 and for every px when
// w%7==0 (in_x = px*w/7 integer); same for fy/rows.  Skipping is bit-exact
// (0.0f * finite == 0.0f, identical f32 expression as the JAX reference)
// and wave-uniform (fx depends only on (px, roi); one px per wave group),
// so the branch compiles to s_cbranch_execz.  Expected ~26% fewer corner
// loads (E[(1+[fx!=0])(1+[fy!=0])]/4 = 0.74).
// ---------------------------------------------------------------------------
__global__ __launch_bounds__(1024) void roi_pool_kernel(
    const float* __restrict__ img,      // (96, 96, 1024)
    const int* __restrict__ rois,       // (600, 4) as (x, y, w, h)
    const int* __restrict__ perm,       // (600,) spatial-sorted roi indices
    float* __restrict__ out)            // (600, 7, 7, 1024)
{
    const int g   = blockIdx.x;         // 0..4199
    const int xcd = g & 7;
    const int i   = g >> 3;             // 0..524
    const int py  = i % POOL;
    const int loc = i / POOL;           // 0..74 within this XCD's chunk
    const int pos = xcd * (NUM_ROIS / 8) + loc;
    const int roi = perm[pos];

    const int4 r = *(const int4*)(rois + roi * 4);
    const int x = r.x;
    const int y = r.y;
    const int w = max(r.z, 1);
    const int h = max(r.w, 1);

    // TF1 resize semantics, f32 op order identical to the JAX reference.
    const float sy = (float)h / (float)POOL;
    const float sx = (float)w / (float)POOL;

    const float in_y = (float)py * sy;
    const int y0 = (int)floorf(in_y);
    const int y1 = min(y0 + 1, h - 1);
    const float fy = in_y - (float)y0;
    const float gy = 1.0f - fy;
    const int R0 = min(max(y + y0, 0), IMG_H - 1);
    const int R1 = min(max(y + y1, 0), IMG_H - 1);

    const int ch = threadIdx.x * 4;
    const float* row0 = img + (size_t)R0 * IMG_W * IMG_C + ch;
    const float* row1 = img + (size_t)R1 * IMG_W * IMG_C + ch;
    float* outp = out + ((size_t)roi * POOL * POOL + (size_t)py * POOL) * IMG_C + ch;

    const bool need_row1 = (fy != 0.0f);   // block-uniform

#pragma unroll
    for (int k = 0; k < 2; ++k) {
        const int px = threadIdx.y + k * 4;
        if (px < POOL) {
            const float in_x = (float)px * sx;
            const int x0 = (int)floorf(in_x);
            const int x1 = min(x0 + 1, w - 1);
            const float fx = in_x - (float)x0;
            const float gx = 1.0f - fx;
            const int C0 = min(max(x + x0, 0), IMG_W - 1);
            const int C1 = min(max(x + x1, 0), IMG_W - 1);

            const bool need_col1 = (fx != 0.0f);   // wave-uniform

            const v4f v00 = *(const v4f*)(row0 + (size_t)C0 * IMG_C);
            v4f v01 = v00, v10 = v00, v11 = v00;
            if (need_col1)
                v01 = *(const v4f*)(row0 + (size_t)C1 * IMG_C);
            if (need_row1) {
                v10 = *(const v4f*)(row1 + (size_t)C0 * IMG_C);
                if (need_col1)
                    v11 = *(const v4f*)(row1 + (size_t)C1 * IMG_C);
            }

            const v4f o = (v00 * gx + v01 * fx) * gy + (v10 * gx + v11 * fx) * fy;

            __builtin_nontemporal_store(o, (v4f*)(outp + (size_t)px * IMG_C));
        }
    }
}

extern "C" void kernel_launch(void* const* d_in, const int* in_sizes, int n_in,
                              void* d_out, int out_size, void* d_ws, size_t ws_size,
                              hipStream_t stream) {
    const float* img  = (const float*)d_in[0];
    const int*   rois = (const int*)d_in[1];
    float*       out  = (float*)d_out;
    int*         perm = (int*)d_ws;      // 600 ints of scratch

    bin_rois_kernel<<<1, 640, 0, stream>>>(rois, perm);
    dim3 block(256, 4, 1);
    roi_pool_kernel<<<NUM_ROIS * POOL, block, 0, stream>>>(img, rois, perm, out);
}